// Round 1
// baseline (177.849 us; speedup 1.0000x reference)
//
#include <hip/hip_runtime.h>
#include <hip/hip_bf16.h>

// SNN spike layer: causal alpha-PSP conv (K<=77) + sequential refractory scan.
// One thread per neuron; time in 15 chunks of 20; register-resident 97-entry
// spike history window; 20 independent FMA chains for ILP at 1 wave/SIMD.

#define T_LEN 300
#define CH 20
#define NCHUNK 15          // 15 * 20 == 300 exactly
#define KS 77              // srm kernel length (alpha, tau=10, eps_tol=0.01)
#define KR 10              // ref kernel tail length (K_ref=11 -> 10 pending slots)
#define THETA_V 10.0f

__global__ __launch_bounds__(256) void spike_layer_kernel(
    const float* __restrict__ spike_in,
    const float* __restrict__ srm, int srm_len,
    const float* __restrict__ refk, int ref_len,
    float* __restrict__ out, int B)
{
    int b = blockIdx.x * blockDim.x + threadIdx.x;
    if (b >= B) return;

    const float* row  = spike_in + (size_t)b * T_LEN;
    float*       orow = out      + (size_t)b * T_LEN;

    // srm taps (wave-uniform loads -> compiler can scalarize)
    float srm_r[KS];
#pragma unroll
    for (int i = 0; i < KS; ++i) srm_r[i] = (i < srm_len) ? srm[i] : 0.0f;

    // refractory tail: ref_kernel[1..], contributions to t+1..t+KR
    float rt[KR];
#pragma unroll
    for (int i = 0; i < KR; ++i) rt[i] = (i + 1 < ref_len) ? refk[i + 1] : 0.0f;

    // history window: hist[i] = s[t0 + i - KS]; hist[KS..KS+CH-1] = current chunk
    float hist[KS + CH];
#pragma unroll
    for (int i = 0; i < KS; ++i) hist[i] = 0.0f;   // t < 0 -> no spikes

    float pend[KR];
#pragma unroll
    for (int i = 0; i < KR; ++i) pend[i] = 0.0f;

    // preload chunk 0
    float nxt[CH];
    {
        const float4* p = (const float4*)row;
#pragma unroll
        for (int i = 0; i < CH / 4; ++i) {
            float4 v = p[i];
            nxt[4*i+0] = v.x; nxt[4*i+1] = v.y; nxt[4*i+2] = v.z; nxt[4*i+3] = v.w;
        }
    }

#pragma unroll 1           // keep the ~2.2k-inst body I-cache resident
    for (int ch = 0; ch < NCHUNK; ++ch) {
        // install current chunk into window tail
#pragma unroll
        for (int i = 0; i < CH; ++i) hist[KS + i] = nxt[i];

        // prefetch next chunk (hidden under the 1540-FMA conv below)
        if (ch + 1 < NCHUNK) {
            const float4* p = (const float4*)(row + (ch + 1) * CH);
#pragma unroll
            for (int i = 0; i < CH / 4; ++i) {
                float4 v = p[i];
                nxt[4*i+0] = v.x; nxt[4*i+1] = v.y; nxt[4*i+2] = v.z; nxt[4*i+3] = v.w;
            }
        }

        // conv: u[t0+c] = sum_j srm[j] * s[t0+c-j]; 20 independent chains
        float u[CH];
#pragma unroll
        for (int c = 0; c < CH; ++c) u[c] = 0.0f;
#pragma unroll
        for (int j = 0; j < KS; ++j) {
            float w = srm_r[j];
#pragma unroll
            for (int c = 0; c < CH; ++c)
                u[c] = fmaf(w, hist[KS + c - j], u[c]);
        }

        // sequential threshold scan with refractory pending queue
        float so[CH];
#pragma unroll
        for (int c = 0; c < CH; ++c) {
            float u_eff = u[c] + pend[0];
            float s = (u_eff >= THETA_V) ? 1.0f : 0.0f;
#pragma unroll
            for (int i = 0; i < KR - 1; ++i) pend[i] = pend[i + 1];
            pend[KR - 1] = 0.0f;
#pragma unroll
            for (int i = 0; i < KR; ++i) pend[i] = fmaf(s, rt[i], pend[i]); // exact: s in {0,1}
            so[c] = s;   // s / TS, TS == 1
        }

        // store chunk
        {
            float4* op = (float4*)(orow + ch * CH);
#pragma unroll
            for (int i = 0; i < CH / 4; ++i) {
                float4 v;
                v.x = so[4*i+0]; v.y = so[4*i+1]; v.z = so[4*i+2]; v.w = so[4*i+3];
                op[i] = v;
            }
        }

        // slide window by CH
#pragma unroll
        for (int i = 0; i < KS; ++i) hist[i] = hist[i + CH];
    }
}

extern "C" void kernel_launch(void* const* d_in, const int* in_sizes, int n_in,
                              void* d_out, int out_size, void* d_ws, size_t ws_size,
                              hipStream_t stream) {
    const float* spike_in = (const float*)d_in[0];
    const float* srm      = (const float*)d_in[1];
    const float* refk     = (const float*)d_in[2];
    float* out = (float*)d_out;

    int srm_len = in_sizes[1];
    int ref_len = in_sizes[2];
    int B = in_sizes[0] / T_LEN;   // 65536 neurons

    int block = 256;
    int grid = (B + block - 1) / block;
    spike_layer_kernel<<<grid, block, 0, stream>>>(spike_in, srm, srm_len,
                                                   refk, ref_len, out, B);
}